// Round 7
// baseline (258.807 us; speedup 1.0000x reference)
//
#include <hip/hip_runtime.h>

// 192^3 structure tensor, fused z-streaming pipeline (4 dispatches):
//   S0: setup_coef     (extract 1D rank-1 factors from the provided 3D kernels)
//   S1: blur3d<6,1>    x -> xs     (xconv in REGISTERS from global; yconv LDS; z reg-ring)
//   S2: gradprod3d<12> xs -> P[6]  (Sx/Dx in registers from global; Sy/Dy LDS; z rings; products)
//   S3: blur3d<24,6>   P -> out    (grouped smoothing, 6 channels)
// LDS discipline (empirical, rounds 4-6): only stride-32 b128 ops (bank = quad-column,
// rows at exact 128 B) — the proven zero-conflict class. No mixed-stride LDS tiles.

constexpr int D  = 192;
constexpr int DD = D * D;                  // 36864
constexpr long long V = (long long)D * DD; // 7077888

// coef layout (floats):
//  [0..6] ga  [7..13] gb  [14..20] gc   (gauss z,y,x)
//  [21..29] az (9)  [30..34] bz (5)  [35..39] cz (5)
//  [40..44] ay (5)  [45..53] by (9)  [54..58] cy (5, dup)
//  [59..63] ax (5)  [64..68] bx (5)  [69..77] cx (9)
__global__ void setup_coef(const float* __restrict__ g3, const float* __restrict__ kz,
                           const float* __restrict__ ky, const float* __restrict__ kx,
                           float* __restrict__ c) {
    if (blockIdx.x != 0 || threadIdx.x != 0) return;
    float Tg = g3[0];
    for (int i = 0; i < 7; ++i) c[0 + i]  = g3[i * 49];
    for (int j = 0; j < 7; ++j) c[7 + j]  = g3[j * 7] / Tg;
    for (int k = 0; k < 7; ++k) c[14 + k] = g3[k] / Tg;
    float Tz = kz[0];                      // kz: [9,5,5]
    for (int i = 0; i < 9; ++i) c[21 + i] = kz[i * 25];
    for (int j = 0; j < 5; ++j) c[30 + j] = kz[j * 5] / Tz;
    for (int k = 0; k < 5; ++k) c[35 + k] = kz[k] / Tz;
    float Ty = ky[0];                      // ky: [5,9,5]
    for (int i = 0; i < 5; ++i) c[40 + i] = ky[i * 45];
    for (int j = 0; j < 9; ++j) c[45 + j] = ky[j * 5] / Ty;
    for (int k = 0; k < 5; ++k) c[54 + k] = ky[k] / Ty;
    float Tx = kx[0];                      // kx: [5,5,9]
    for (int i = 0; i < 5; ++i) c[59 + i] = kx[i * 45];
    for (int j = 0; j < 5; ++j) c[64 + j] = kx[j * 9] / Tx;
    for (int k = 0; k < 9; ++k) c[69 + k] = kx[k] / Tx;
}

// Bounds-checked float4 load from one z-slice (row gy, cols gx..gx+3), zero-padded.
__device__ inline float4 ldg4(const float* __restrict__ slice, int gy, int gx) {
    float4 v = {0.f, 0.f, 0.f, 0.f};
    if ((unsigned)gy < (unsigned)D) {
        const float* row = slice + gy * D;
        if ((unsigned)gx <= (unsigned)(D - 4)) {
            v = *(const float4*)(row + gx);
        } else {
            float* pv = (float*)&v;
#pragma unroll
            for (int j = 0; j < 4; ++j) {
                const int g = gx + j;
                if ((unsigned)g < (unsigned)D) pv[j] = row[g];
            }
        }
    }
    return v;
}

// ---- fused separable 3D blur, z-streaming, 32x32 tile, register z-ring ----
// 1D grid, XCD-swizzled; work = tile + 36*(ch + NCH*seg)
template <int SEG, int NCH>
__global__ __launch_bounds__(256) void blur3d(const float* __restrict__ in,
                                              float* __restrict__ out,
                                              const float* __restrict__ coef) {
    __shared__ float xt[38][32];
    const int cpx = gridDim.x >> 3;
    int w = (blockIdx.x & 7) * cpx + (blockIdx.x >> 3);
    const int tile = w % 36; w /= 36;
    const int ch = w % NCH;
    const int seg = w / NCH;
    const int tx0 = (tile % 6) * 32, ty0 = (tile / 6) * 32;
    const int z0 = seg * SEG;
    const float* src = in + (long long)ch * V;
    float* dst = out + (long long)ch * V;
    float ga[7], gb[7], gc[7];
#pragma unroll
    for (int k = 0; k < 7; ++k) { ga[k] = coef[k]; gb[k] = coef[7 + k]; gc[k] = coef[14 + k]; }
    const int rr = threadIdx.x >> 3;          // 0..31
    const int cc = (threadIdx.x & 7) * 4;     // 0,4,..,28
    // xconv task 0: li = tid (r0, f40); task 1: li = tid+256 (only tid<48)
    const int r0 = threadIdx.x >> 3,        f40 = (threadIdx.x & 7) * 4;
    const int r1 = (threadIdx.x + 256) >> 3, f41 = f40;
    const bool has1 = threadIdx.x < 48;     // 304 - 256
    float4 ring[7];
#pragma unroll
    for (int k = 0; k < 7; ++k) ring[k] = make_float4(0.f, 0.f, 0.f, 0.f);

    for (int s = z0 - 3; s < z0 + SEG + 3; ++s) {
        const bool inz = (s >= 0 && s < D);
        float4 o0 = make_float4(0.f, 0.f, 0.f, 0.f);
        float4 o1 = make_float4(0.f, 0.f, 0.f, 0.f);
        if (inz) {
            const float* slice = src + (long long)s * DD;
            {
                const float4 A = ldg4(slice, ty0 - 3 + r0, tx0 + f40 - 4);
                const float4 B = ldg4(slice, ty0 - 3 + r0, tx0 + f40);
                const float4 C = ldg4(slice, ty0 - 3 + r0, tx0 + f40 + 4);
                const float win[12] = {A.x, A.y, A.z, A.w, B.x, B.y, B.z, B.w,
                                       C.x, C.y, C.z, C.w};
#pragma unroll
                for (int k = 0; k < 7; ++k) {
                    o0.x += gc[k] * win[1 + k];
                    o0.y += gc[k] * win[2 + k];
                    o0.z += gc[k] * win[3 + k];
                    o0.w += gc[k] * win[4 + k];
                }
            }
            if (has1) {
                const float4 A = ldg4(slice, ty0 - 3 + r1, tx0 + f41 - 4);
                const float4 B = ldg4(slice, ty0 - 3 + r1, tx0 + f41);
                const float4 C = ldg4(slice, ty0 - 3 + r1, tx0 + f41 + 4);
                const float win[12] = {A.x, A.y, A.z, A.w, B.x, B.y, B.z, B.w,
                                       C.x, C.y, C.z, C.w};
#pragma unroll
                for (int k = 0; k < 7; ++k) {
                    o1.x += gc[k] * win[1 + k];
                    o1.y += gc[k] * win[2 + k];
                    o1.z += gc[k] * win[3 + k];
                    o1.w += gc[k] * win[4 + k];
                }
            }
        }
        __syncthreads();                       // prior yconv readers done
        if (inz) {
            *(float4*)&xt[r0][f40] = o0;
            if (has1) *(float4*)&xt[r1][f41] = o1;
        }
        __syncthreads();                       // xt ready
        float4 yv = make_float4(0.f, 0.f, 0.f, 0.f);
        if (inz) {
#pragma unroll
            for (int k = 0; k < 7; ++k) {
                const float4 v = *(const float4*)&xt[rr + k][cc];
                yv.x += gb[k] * v.x; yv.y += gb[k] * v.y;
                yv.z += gb[k] * v.z; yv.w += gb[k] * v.w;
            }
        }
#pragma unroll
        for (int k = 0; k < 6; ++k) ring[k] = ring[k + 1];
        ring[6] = yv;
        const int z = s - 3;
        if (z >= z0) {
            float4 a = make_float4(0.f, 0.f, 0.f, 0.f);
#pragma unroll
            for (int k = 0; k < 7; ++k) {
                a.x += ga[k] * ring[k].x; a.y += ga[k] * ring[k].y;
                a.z += ga[k] * ring[k].z; a.w += ga[k] * ring[k].w;
            }
            *(float4*)(dst + (long long)z * DD + (ty0 + rr) * D + tx0 + cc) = a;
        }
    }
}

// ---- fused gradients + products, z-streaming, 32x16 tile, register rings ----
// 1D grid, XCD-swizzled; work = tile + 72*seg
template <int SEG>
__global__ __launch_bounds__(256) void gradprod3d(const float* __restrict__ xs,
                                                  float* __restrict__ P,
                                                  const float* __restrict__ coef) {
    __shared__ float X1[24][32];
    __shared__ float X2[24][32];
    const int cpx = gridDim.x >> 3;
    int w = (blockIdx.x & 7) * cpx + (blockIdx.x >> 3);
    const int tile = w % 72;
    const int seg = w / 72;
    const int tx0 = (tile % 6) * 32, ty0 = (tile / 6) * 16;
    const int z0 = seg * SEG;
    float az[9], ay[5], ax[5], bz[5], by[9], bx[5], czc[5], cxc[9];
#pragma unroll
    for (int k = 0; k < 9; ++k) az[k] = coef[21 + k];
#pragma unroll
    for (int k = 0; k < 5; ++k) ay[k] = coef[40 + k];
#pragma unroll
    for (int k = 0; k < 5; ++k) ax[k] = coef[59 + k];
#pragma unroll
    for (int k = 0; k < 5; ++k) bz[k] = coef[30 + k];
#pragma unroll
    for (int k = 0; k < 9; ++k) by[k] = coef[45 + k];
#pragma unroll
    for (int k = 0; k < 5; ++k) bx[k] = coef[64 + k];
#pragma unroll
    for (int k = 0; k < 5; ++k) czc[k] = coef[35 + k];
#pragma unroll
    for (int k = 0; k < 9; ++k) cxc[k] = coef[69 + k];
    const int rr = threadIdx.x >> 4;           // 0..15
    const int cc = (threadIdx.x & 15) * 2;     // 0,2,..,30
    const int xr = threadIdx.x >> 3;           // xconv task row 0..23 (tid<192)
    const int xf = (threadIdx.x & 7) * 4;
    const bool hasx = threadIdx.x < 192;
    float2 R1[9], R2[7], R3[7];
#pragma unroll
    for (int k = 0; k < 9; ++k) R1[k] = make_float2(0.f, 0.f);
#pragma unroll
    for (int k = 0; k < 7; ++k) { R2[k] = make_float2(0.f, 0.f); R3[k] = make_float2(0.f, 0.f); }

    for (int s = z0 - 4; s < z0 + SEG + 4; ++s) {
        const bool inz = (s >= 0 && s < D);
        float4 o1 = make_float4(0.f, 0.f, 0.f, 0.f);
        float4 o2 = make_float4(0.f, 0.f, 0.f, 0.f);
        if (inz && hasx) {
            const float* slice = xs + (long long)s * DD;
            const float4 A = ldg4(slice, ty0 - 4 + xr, tx0 + xf - 4);
            const float4 B = ldg4(slice, ty0 - 4 + xr, tx0 + xf);
            const float4 C = ldg4(slice, ty0 - 4 + xr, tx0 + xf + 4);
            const float win[12] = {A.x, A.y, A.z, A.w, B.x, B.y, B.z, B.w,
                                   C.x, C.y, C.z, C.w};
#pragma unroll
            for (int k = 0; k < 5; ++k) {
                o1.x += czc[k] * win[2 + k];
                o1.y += czc[k] * win[3 + k];
                o1.z += czc[k] * win[4 + k];
                o1.w += czc[k] * win[5 + k];
            }
#pragma unroll
            for (int k = 0; k < 9; ++k) {
                o2.x += cxc[k] * win[0 + k];
                o2.y += cxc[k] * win[1 + k];
                o2.z += cxc[k] * win[2 + k];
                o2.w += cxc[k] * win[3 + k];
            }
        }
        __syncthreads();                       // prior yconv readers done
        if (inz && hasx) {
            *(float4*)&X1[xr][xf] = o1;
            *(float4*)&X2[xr][xf] = o2;
        }
        __syncthreads();                       // X1/X2 ready
        float2 t1 = make_float2(0.f, 0.f), t2 = t1, t3 = t1;
        if (inz) {
#pragma unroll
            for (int k = 0; k < 5; ++k) {
                const float2 v = *(const float2*)&X1[rr + 2 + k][cc];
                t1.x += bz[k] * v.x; t1.y += bz[k] * v.y;
            }
#pragma unroll
            for (int k = 0; k < 9; ++k) {
                const float2 v = *(const float2*)&X1[rr + k][cc];
                t2.x += by[k] * v.x; t2.y += by[k] * v.y;
            }
#pragma unroll
            for (int k = 0; k < 5; ++k) {
                const float2 v = *(const float2*)&X2[rr + 2 + k][cc];
                t3.x += bx[k] * v.x; t3.y += bx[k] * v.y;
            }
        }
#pragma unroll
        for (int k = 0; k < 8; ++k) R1[k] = R1[k + 1];
        R1[8] = t1;
#pragma unroll
        for (int k = 0; k < 6; ++k) { R2[k] = R2[k + 1]; R3[k] = R3[k + 1]; }
        R2[6] = t2; R3[6] = t3;
        const int z = s - 4;
        if (z >= z0) {
            float gz0 = 0.f, gz1 = 0.f, gy0 = 0.f, gy1 = 0.f, gx0 = 0.f, gx1 = 0.f;
#pragma unroll
            for (int k = 0; k < 9; ++k) { gz0 += az[k] * R1[k].x; gz1 += az[k] * R1[k].y; }
#pragma unroll
            for (int k = 0; k < 5; ++k) {
                gy0 += ay[k] * R2[k].x; gy1 += ay[k] * R2[k].y;
                gx0 += ax[k] * R3[k].x; gx1 += ax[k] * R3[k].y;
            }
            float* o = P + (long long)z * DD + (ty0 + rr) * D + tx0 + cc;
            float2 wv;
            wv.x = gz0 * gz0; wv.y = gz1 * gz1; *(float2*)(o + 0 * V) = wv;
            wv.x = gy0 * gz0; wv.y = gy1 * gz1; *(float2*)(o + 1 * V) = wv;
            wv.x = gx0 * gz0; wv.y = gx1 * gz1; *(float2*)(o + 2 * V) = wv;
            wv.x = gy0 * gy0; wv.y = gy1 * gy1; *(float2*)(o + 3 * V) = wv;
            wv.x = gx0 * gy0; wv.y = gx1 * gy1; *(float2*)(o + 4 * V) = wv;
            wv.x = gx0 * gx0; wv.y = gx1 * gx1; *(float2*)(o + 5 * V) = wv;
        }
    }
}

extern "C" void kernel_launch(void* const* d_in, const int* in_sizes, int n_in,
                              void* d_out, int out_size, void* d_ws, size_t ws_size,
                              hipStream_t stream) {
    const float* x  = (const float*)d_in[0];
    const float* g3 = (const float*)d_in[1];
    const float* kz = (const float*)d_in[2];
    const float* ky = (const float*)d_in[3];
    const float* kx = (const float*)d_in[4];
    float* out = (float*)d_out;

    float* coef = (float*)d_ws;
    float* P  = coef + 128;          // 6*V floats
    float* xs = P + 6 * V;           // V floats

    setup_coef<<<1, 64, 0, stream>>>(g3, kz, ky, kx, coef);

    // S1: Gaussian pre-smooth  x -> xs   (36 tiles x 32 segs = 1152 blocks)
    blur3d<6, 1><<<1152, 256, 0, stream>>>(x, xs, coef);

    // S2: gradients + products  xs -> P  (72 tiles x 16 segs = 1152 blocks)
    gradprod3d<12><<<1152, 256, 0, stream>>>(xs, P, coef);

    // S3: grouped smoothing  P -> out    (36 tiles x 6 ch x 8 segs = 1728 blocks)
    blur3d<24, 6><<<1728, 256, 0, stream>>>(P, out, coef);
}

// Round 8
// 177.761 us; speedup vs baseline: 1.4559x; 1.4559x over previous
//
#include <hip/hip_runtime.h>

// 192^3 structure tensor, fused z-streaming pipeline (4 dispatches):
//   S0: setup_coef     (extract 1D rank-1 factors from the provided 3D kernels)
//   S1: blur3d<6,1>    x -> xs     (sliding-window xconv from stride-41 LDS; yconv b128; z reg-ring)
//   S2: gradprod3d<12> xs -> P[6]  (shared 12-read window for Sx&Dx; Sy/Dy float2; z rings; products)
//   S3: blur3d<24,6>   P -> out    (grouped smoothing, 6 channels)
// LDS op classes (empirical r3-r7): scalar b32 any map = free; b128 on stride-32 rows
// (8-row x 8-quad map) = free; b128 at stride!=0 mod 32 = conflicted; per-thread windowed
// global loads = latency-bound. Stride-41 sliding reads: bank = 9r+4g+i, multiplicity <= 2.

constexpr int D  = 192;
constexpr int DD = D * D;                  // 36864
constexpr long long V = (long long)D * DD; // 7077888

// coef layout (floats):
//  [0..6] ga  [7..13] gb  [14..20] gc   (gauss z,y,x)
//  [21..29] az (9)  [30..34] bz (5)  [35..39] cz (5)
//  [40..44] ay (5)  [45..53] by (9)  [54..58] cy (5, dup)
//  [59..63] ax (5)  [64..68] bx (5)  [69..77] cx (9)
__global__ void setup_coef(const float* __restrict__ g3, const float* __restrict__ kz,
                           const float* __restrict__ ky, const float* __restrict__ kx,
                           float* __restrict__ c) {
    if (blockIdx.x != 0 || threadIdx.x != 0) return;
    float Tg = g3[0];
    for (int i = 0; i < 7; ++i) c[0 + i]  = g3[i * 49];
    for (int j = 0; j < 7; ++j) c[7 + j]  = g3[j * 7] / Tg;
    for (int k = 0; k < 7; ++k) c[14 + k] = g3[k] / Tg;
    float Tz = kz[0];                      // kz: [9,5,5]
    for (int i = 0; i < 9; ++i) c[21 + i] = kz[i * 25];
    for (int j = 0; j < 5; ++j) c[30 + j] = kz[j * 5] / Tz;
    for (int k = 0; k < 5; ++k) c[35 + k] = kz[k] / Tz;
    float Ty = ky[0];                      // ky: [5,9,5]
    for (int i = 0; i < 5; ++i) c[40 + i] = ky[i * 45];
    for (int j = 0; j < 9; ++j) c[45 + j] = ky[j * 5] / Ty;
    for (int k = 0; k < 5; ++k) c[54 + k] = ky[k] / Ty;
    float Tx = kx[0];                      // kx: [5,5,9]
    for (int i = 0; i < 5; ++i) c[59 + i] = kx[i * 45];
    for (int j = 0; j < 5; ++j) c[64 + j] = kx[j * 9] / Tx;
    for (int k = 0; k < 9; ++k) c[69 + k] = kx[k] / Tx;
}

// Load a (rows x 40)-float region of one z-slice into stride-41 LDS, zero-padded.
// Scalar b32 writes (stride 41 is not 16B-aligned per row; b32 class is conflict-free).
__device__ inline void load_slice41(const float* __restrict__ src, float* __restrict__ dst,
                                    int rows, int y0, int x0) {
    const int nq = rows * 10;
    for (int li = threadIdx.x; li < nq; li += 256) {
        const int r = li / 10, q = li % 10;
        const int gy = y0 + r, gx = x0 + q * 4;
        float4 v = {0.f, 0.f, 0.f, 0.f};
        if (gy >= 0 && gy < D) {
            if (gx >= 0 && gx + 3 < D) {
                v = *(const float4*)(src + gy * D + gx);
            } else {
                float* pv = (float*)&v;
                for (int j = 0; j < 4; ++j) {
                    const int g = gx + j;
                    if (g >= 0 && g < D) pv[j] = src[gy * D + g];
                }
            }
        }
        float* d = &dst[r * 41 + q * 4];
        d[0] = v.x; d[1] = v.y; d[2] = v.z; d[3] = v.w;
    }
}

// ---- fused separable 3D blur, z-streaming, 32x32 tile, register z-ring ----
// 1D grid, XCD-swizzled; work = tile + 36*(ch + NCH*seg)
template <int SEG, int NCH>
__global__ __launch_bounds__(256) void blur3d(const float* __restrict__ in,
                                              float* __restrict__ out,
                                              const float* __restrict__ coef) {
    __shared__ float raw[38 * 41];
    __shared__ float xt[38][32];
    const int cpx = gridDim.x >> 3;
    int w = (blockIdx.x & 7) * cpx + (blockIdx.x >> 3);
    const int tile = w % 36; w /= 36;
    const int ch = w % NCH;
    const int seg = w / NCH;
    const int tx0 = (tile % 6) * 32, ty0 = (tile / 6) * 32;
    const int z0 = seg * SEG;
    const float* src = in + (long long)ch * V;
    float* dst = out + (long long)ch * V;
    float ga[7], gb[7], gc[7];
#pragma unroll
    for (int k = 0; k < 7; ++k) { ga[k] = coef[k]; gb[k] = coef[7 + k]; gc[k] = coef[14 + k]; }
    const int rr = threadIdx.x >> 3;          // 0..31
    const int cc = (threadIdx.x & 7) * 4;     // 0,4,..,28
    float4 ring[7];
#pragma unroll
    for (int k = 0; k < 7; ++k) ring[k] = make_float4(0.f, 0.f, 0.f, 0.f);

    for (int s = z0 - 3; s < z0 + SEG + 3; ++s) {
        const bool inz = (s >= 0 && s < D);
        if (inz) load_slice41(src + (long long)s * DD, raw, 38, ty0 - 3, tx0 - 4);
        __syncthreads();                       // raw ready; prior yconv xt-readers done
        if (inz) {
            // 4-output sliding-window xconv: 10 scalar reads -> 4 outputs, b128 xt write
            for (int li = threadIdx.x; li < 38 * 8; li += 256) {
                const int r = li >> 3, g = li & 7;
                const float* rp = &raw[r * 41 + 4 * g + 1];
                float win[10];
#pragma unroll
                for (int i = 0; i < 10; ++i) win[i] = rp[i];
                float4 o = make_float4(0.f, 0.f, 0.f, 0.f);
#pragma unroll
                for (int k = 0; k < 7; ++k) {
                    o.x += gc[k] * win[k];
                    o.y += gc[k] * win[k + 1];
                    o.z += gc[k] * win[k + 2];
                    o.w += gc[k] * win[k + 3];
                }
                *(float4*)&xt[r][4 * g] = o;
            }
        }
        __syncthreads();                       // xt ready; raw readers done
        float4 yv = make_float4(0.f, 0.f, 0.f, 0.f);
        if (inz) {
#pragma unroll
            for (int k = 0; k < 7; ++k) {
                const float4 v = *(const float4*)&xt[rr + k][cc];
                yv.x += gb[k] * v.x; yv.y += gb[k] * v.y;
                yv.z += gb[k] * v.z; yv.w += gb[k] * v.w;
            }
        }
#pragma unroll
        for (int k = 0; k < 6; ++k) ring[k] = ring[k + 1];
        ring[6] = yv;
        const int z = s - 3;
        if (z >= z0) {
            float4 a = make_float4(0.f, 0.f, 0.f, 0.f);
#pragma unroll
            for (int k = 0; k < 7; ++k) {
                a.x += ga[k] * ring[k].x; a.y += ga[k] * ring[k].y;
                a.z += ga[k] * ring[k].z; a.w += ga[k] * ring[k].w;
            }
            *(float4*)(dst + (long long)z * DD + (ty0 + rr) * D + tx0 + cc) = a;
        }
    }
}

// ---- fused gradients + products, z-streaming, 32x16 tile, register rings ----
// 1D grid, XCD-swizzled; work = tile + 72*seg
template <int SEG>
__global__ __launch_bounds__(256) void gradprod3d(const float* __restrict__ xs,
                                                  float* __restrict__ P,
                                                  const float* __restrict__ coef) {
    __shared__ float raw[24 * 41];
    __shared__ float X1[24][32];
    __shared__ float X2[24][32];
    const int cpx = gridDim.x >> 3;
    int w = (blockIdx.x & 7) * cpx + (blockIdx.x >> 3);
    const int tile = w % 72;
    const int seg = w / 72;
    const int tx0 = (tile % 6) * 32, ty0 = (tile / 6) * 16;
    const int z0 = seg * SEG;
    float az[9], ay[5], ax[5], bz[5], by[9], bx[5], czc[5], cxc[9];
#pragma unroll
    for (int k = 0; k < 9; ++k) az[k] = coef[21 + k];
#pragma unroll
    for (int k = 0; k < 5; ++k) ay[k] = coef[40 + k];
#pragma unroll
    for (int k = 0; k < 5; ++k) ax[k] = coef[59 + k];
#pragma unroll
    for (int k = 0; k < 5; ++k) bz[k] = coef[30 + k];
#pragma unroll
    for (int k = 0; k < 9; ++k) by[k] = coef[45 + k];
#pragma unroll
    for (int k = 0; k < 5; ++k) bx[k] = coef[64 + k];
#pragma unroll
    for (int k = 0; k < 5; ++k) czc[k] = coef[35 + k];
#pragma unroll
    for (int k = 0; k < 9; ++k) cxc[k] = coef[69 + k];
    const int rr = threadIdx.x >> 4;           // 0..15
    const int cc = (threadIdx.x & 15) * 2;     // 0,2,..,30
    float2 R1[9], R2[7], R3[7];
#pragma unroll
    for (int k = 0; k < 9; ++k) R1[k] = make_float2(0.f, 0.f);
#pragma unroll
    for (int k = 0; k < 7; ++k) { R2[k] = make_float2(0.f, 0.f); R3[k] = make_float2(0.f, 0.f); }

    for (int s = z0 - 4; s < z0 + SEG + 4; ++s) {
        const bool inz = (s >= 0 && s < D);
        if (inz) load_slice41(xs + (long long)s * DD, raw, 24, ty0 - 4, tx0 - 4);
        __syncthreads();                       // raw ready; prior X readers done
        if (inz && threadIdx.x < 192) {
            // 12-read window serves the 5-tap (X1) and 9-tap (X2) x-convs, 4 outputs each
            const int r = threadIdx.x >> 3, g = threadIdx.x & 7;
            const float* rp = &raw[r * 41 + 4 * g];
            float win[12];
#pragma unroll
            for (int i = 0; i < 12; ++i) win[i] = rp[i];
            float4 o1 = make_float4(0.f, 0.f, 0.f, 0.f);
            float4 o2 = make_float4(0.f, 0.f, 0.f, 0.f);
#pragma unroll
            for (int k = 0; k < 5; ++k) {
                o1.x += czc[k] * win[2 + k];
                o1.y += czc[k] * win[3 + k];
                o1.z += czc[k] * win[4 + k];
                o1.w += czc[k] * win[5 + k];
            }
#pragma unroll
            for (int k = 0; k < 9; ++k) {
                o2.x += cxc[k] * win[k];
                o2.y += cxc[k] * win[1 + k];
                o2.z += cxc[k] * win[2 + k];
                o2.w += cxc[k] * win[3 + k];
            }
            *(float4*)&X1[r][4 * g] = o1;
            *(float4*)&X2[r][4 * g] = o2;
        }
        __syncthreads();                       // X1/X2 ready; raw readers done
        float2 t1 = make_float2(0.f, 0.f), t2 = t1, t3 = t1;
        if (inz) {
#pragma unroll
            for (int k = 0; k < 5; ++k) {
                const float2 v = *(const float2*)&X1[rr + 2 + k][cc];
                t1.x += bz[k] * v.x; t1.y += bz[k] * v.y;
            }
#pragma unroll
            for (int k = 0; k < 9; ++k) {
                const float2 v = *(const float2*)&X1[rr + k][cc];
                t2.x += by[k] * v.x; t2.y += by[k] * v.y;
            }
#pragma unroll
            for (int k = 0; k < 5; ++k) {
                const float2 v = *(const float2*)&X2[rr + 2 + k][cc];
                t3.x += bx[k] * v.x; t3.y += bx[k] * v.y;
            }
        }
#pragma unroll
        for (int k = 0; k < 8; ++k) R1[k] = R1[k + 1];
        R1[8] = t1;
#pragma unroll
        for (int k = 0; k < 6; ++k) { R2[k] = R2[k + 1]; R3[k] = R3[k + 1]; }
        R2[6] = t2; R3[6] = t3;
        const int z = s - 4;
        if (z >= z0) {
            float gz0 = 0.f, gz1 = 0.f, gy0 = 0.f, gy1 = 0.f, gx0 = 0.f, gx1 = 0.f;
#pragma unroll
            for (int k = 0; k < 9; ++k) { gz0 += az[k] * R1[k].x; gz1 += az[k] * R1[k].y; }
#pragma unroll
            for (int k = 0; k < 5; ++k) {
                gy0 += ay[k] * R2[k].x; gy1 += ay[k] * R2[k].y;
                gx0 += ax[k] * R3[k].x; gx1 += ax[k] * R3[k].y;
            }
            float* o = P + (long long)z * DD + (ty0 + rr) * D + tx0 + cc;
            float2 wv;
            wv.x = gz0 * gz0; wv.y = gz1 * gz1; *(float2*)(o + 0 * V) = wv;
            wv.x = gy0 * gz0; wv.y = gy1 * gz1; *(float2*)(o + 1 * V) = wv;
            wv.x = gx0 * gz0; wv.y = gx1 * gz1; *(float2*)(o + 2 * V) = wv;
            wv.x = gy0 * gy0; wv.y = gy1 * gy1; *(float2*)(o + 3 * V) = wv;
            wv.x = gx0 * gy0; wv.y = gx1 * gy1; *(float2*)(o + 4 * V) = wv;
            wv.x = gx0 * gx0; wv.y = gx1 * gx1; *(float2*)(o + 5 * V) = wv;
        }
    }
}

extern "C" void kernel_launch(void* const* d_in, const int* in_sizes, int n_in,
                              void* d_out, int out_size, void* d_ws, size_t ws_size,
                              hipStream_t stream) {
    const float* x  = (const float*)d_in[0];
    const float* g3 = (const float*)d_in[1];
    const float* kz = (const float*)d_in[2];
    const float* ky = (const float*)d_in[3];
    const float* kx = (const float*)d_in[4];
    float* out = (float*)d_out;

    float* coef = (float*)d_ws;
    float* P  = coef + 128;          // 6*V floats
    float* xs = P + 6 * V;           // V floats

    setup_coef<<<1, 64, 0, stream>>>(g3, kz, ky, kx, coef);

    // S1: Gaussian pre-smooth  x -> xs   (36 tiles x 32 segs = 1152 blocks)
    blur3d<6, 1><<<1152, 256, 0, stream>>>(x, xs, coef);

    // S2: gradients + products  xs -> P  (72 tiles x 16 segs = 1152 blocks)
    gradprod3d<12><<<1152, 256, 0, stream>>>(xs, P, coef);

    // S3: grouped smoothing  P -> out    (36 tiles x 6 ch x 8 segs = 1728 blocks)
    blur3d<24, 6><<<1728, 256, 0, stream>>>(P, out, coef);
}